// Round 3
// baseline (133.084 us; speedup 1.0000x reference)
//
#include <hip/hip_runtime.h>
#include <hip/hip_bf16.h>
#include <math.h>

// Problem constants: B=256, V=2048, PD=1024, MD=512, H=512
typedef __attribute__((ext_vector_type(8))) short short8;
typedef __attribute__((ext_vector_type(4))) short short4v;
typedef __attribute__((ext_vector_type(4))) float float4v;
typedef __attribute__((ext_vector_type(2))) float float2v;

__device__ __forceinline__ short f2bf(float f) {
    union { float f; unsigned u; } x; x.f = f;
    unsigned r = (x.u + 0x7FFFu + ((x.u >> 16) & 1u)) >> 16; // RNE
    return (short)r;
}

// Fused dual GEMM + exp epilogue, outputs in h-PAIRED layout:
//   T2[(h>>1)*(2M) + x*2 + (h&1)] = exp(2*(C[x][h] + bias[h]))
// so phase 2 can read (e_h, e_{h+1}) for one x as an adjacent float2.
//  z==0: EA2 from patient@W1p^T + b1   (M=256,  K=1024); idle blocks init out=b2
//  z==1: EM2 from atc4@W1m^T           (M=2048, K=512)
__global__ __launch_bounds__(256) void gemm_exp(
    const float* __restrict__ patient, const float* __restrict__ atc4,
    const float* __restrict__ W1, const float* __restrict__ b1,
    const float* __restrict__ b2,
    float* __restrict__ EA2, float* __restrict__ EM2, float* __restrict__ out)
{
    const float* A; const float* W; const float* bias; float* T;
    int lda, K, M;
    if (blockIdx.z == 0) {
        if (blockIdx.x >= 4) {
            // 224 spare blocks: initialize out = b2 (out is re-poisoned every call)
            const float bb = b2[0];
            float4v bb4 = { bb, bb, bb, bb };
            const int fid = (blockIdx.x - 4) * 8 + blockIdx.y;  // 0..223
            for (int i = fid * 256 + threadIdx.x; i < 131072; i += 224 * 256)
                ((float4v*)out)[i] = bb4;
            return;
        }
        A = patient; lda = 1024; K = 1024; M = 256; bias = b1; T = EA2; W = W1;
    } else {
        A = atc4;    lda = 512;  K = 512;  M = 2048; bias = nullptr; T = EM2; W = W1 + 1024;
    }
    const int ldw = 1536;

    __shared__ short As[64][72];
    __shared__ short Bs[64][72];
    const int t = threadIdx.x;
    const int m0 = blockIdx.x * 64;
    const int n0 = blockIdx.y * 64;
    const int wave = t >> 6;
    const int lane = t & 63;
    const int wm = (wave & 1) * 32;
    const int wn = (wave >> 1) * 32;
    const int lrow = lane & 15;
    const int quad = lane >> 4;

    float4v acc[2][2];
    #pragma unroll
    for (int i = 0; i < 2; i++)
        #pragma unroll
        for (int j = 0; j < 2; j++)
            acc[i][j] = (float4v){0.f, 0.f, 0.f, 0.f};

    const int sr = t >> 2;        // staging row 0..63
    const int sc = (t & 3) * 16;  // staging col 0,16,32,48

    for (int k0 = 0; k0 < K; k0 += 64) {
        const float* ap = A + (size_t)(m0 + sr) * lda + (k0 + sc);
        const float* wp = W + (size_t)(n0 + sr) * ldw + (k0 + sc);
        #pragma unroll
        for (int ii = 0; ii < 4; ii++) {
            float4v av = *(const float4v*)(ap + ii * 4);
            float4v wv = *(const float4v*)(wp + ii * 4);
            short4v a4 = { f2bf(av.x), f2bf(av.y), f2bf(av.z), f2bf(av.w) };
            short4v w4 = { f2bf(wv.x), f2bf(wv.y), f2bf(wv.z), f2bf(wv.w) };
            *(short4v*)&As[sr][sc + ii * 4] = a4;
            *(short4v*)&Bs[sr][sc + ii * 4] = w4;
        }
        __syncthreads();
        #pragma unroll
        for (int kk = 0; kk < 64; kk += 32) {
            short8 af[2], bfr[2];
            #pragma unroll
            for (int i = 0; i < 2; i++)
                af[i] = *(const short8*)&As[wm + i * 16 + lrow][kk + quad * 8];
            #pragma unroll
            for (int j = 0; j < 2; j++)
                bfr[j] = *(const short8*)&Bs[wn + j * 16 + lrow][kk + quad * 8];
            #pragma unroll
            for (int i = 0; i < 2; i++)
                #pragma unroll
                for (int j = 0; j < 2; j++)
                    acc[i][j] = __builtin_amdgcn_mfma_f32_16x16x32_bf16(
                        af[i], bfr[j], acc[i][j], 0, 0, 0);
        }
        __syncthreads();
    }

    // D layout (verified m89/m91): col(n)=lane&15, row(m)=quad*4+reg
    // n is the h dimension; scatter into paired layout (stride-2 dword stores).
    #pragma unroll
    for (int i = 0; i < 2; i++) {
        #pragma unroll
        for (int j = 0; j < 2; j++) {
            const int n  = n0 + wn + j * 16 + lrow;
            const int mb = m0 + wm + i * 16 + quad * 4;
            const float bn = bias ? bias[n] : 0.0f;
            const size_t base = (size_t)(n >> 1) * (2 * M) + (n & 1);
            #pragma unroll
            for (int r = 0; r < 4; r++)
                T[base + (size_t)(mb + r) * 2] = __expf(2.0f * (acc[i][j][r] + bn));
        }
    }
}

// out[b][v] += sum_{h in chunk} w2[h]*tanh(a+m), via
//   w2*tanh = w2 + c/d,  c = -2*w2, d = 1 + Ea*Em
// h-PAIRED: c0/d0 + c1/d1 = (c0*d1 + c1*d0) / (d0*d1)  -> one rcp per 2 h-terms.
// Tile: 64 v x 32 b x 128 h. Grid (32, 8, 4) = 1024 blocks.
__global__ __launch_bounds__(256) void pair_kernel(
    const float* __restrict__ EA2, const float* __restrict__ EM2,
    const float* __restrict__ w2, float* __restrict__ out)
{
    __shared__ float sEA[32][68];    // [hp][2*b]  64 cols used
    __shared__ float sEM[32][132];   // [hp][2*v]  128 cols used
    __shared__ float2v sC[64];       // (-2w2[2hp], -2w2[2hp+1]) for the 128-h chunk
    const int t  = threadIdx.x;
    const int v0 = blockIdx.x * 64;
    const int b0 = blockIdx.y * 32;
    const int h0 = blockIdx.z * 128;
    const int tx = t & 15;   // v = v0 + tx*4 + j
    const int ty = t >> 4;   // b = b0 + ty*2 + i

    if (t < 64) {
        float2v c = { -2.0f * w2[h0 + 2 * t], -2.0f * w2[h0 + 2 * t + 1] };
        sC[t] = c;
    }

    float acc[2][4];
    #pragma unroll
    for (int i = 0; i < 2; i++)
        #pragma unroll
        for (int j = 0; j < 4; j++)
            acc[i][j] = 0.0f;

    const int rS = t >> 3;          // staging row 0..31
    const int cS = (t & 7) * 8;     // EA cols (64/row)
    const int cM = (t & 7) * 16;    // EM cols (128/row)

    for (int half = 0; half < 2; half++) {
        const int hpb = (h0 >> 1) + half * 32;
        {
            const float* pa = EA2 + (size_t)(hpb + rS) * 512 + b0 * 2 + cS;
            *(float4v*)&sEA[rS][cS]     = *(const float4v*)pa;
            *(float4v*)&sEA[rS][cS + 4] = *(const float4v*)(pa + 4);
            const float* pm = EM2 + (size_t)(hpb + rS) * 4096 + v0 * 2 + cM;
            *(float4v*)&sEM[rS][cM]      = *(const float4v*)pm;
            *(float4v*)&sEM[rS][cM + 4]  = *(const float4v*)(pm + 4);
            *(float4v*)&sEM[rS][cM + 8]  = *(const float4v*)(pm + 8);
            *(float4v*)&sEM[rS][cM + 12] = *(const float4v*)(pm + 12);
        }
        __syncthreads();
        #pragma unroll 2
        for (int hp = 0; hp < 32; hp++) {
            const float4v ea4  = *(const float4v*)&sEA[hp][ty * 4];
            const float4v em01 = *(const float4v*)&sEM[hp][tx * 8];
            const float4v em23 = *(const float4v*)&sEM[hp][tx * 8 + 4];
            const float2v c = sC[half * 32 + hp];
            float2v eaP[2] = { { ea4.x, ea4.y }, { ea4.z, ea4.w } };
            float2v emP[4] = { { em01.x, em01.y }, { em01.z, em01.w },
                               { em23.x, em23.y }, { em23.z, em23.w } };
            #pragma unroll
            for (int i = 0; i < 2; i++) {
                #pragma unroll
                for (int j = 0; j < 4; j++) {
                    float2v d = __builtin_elementwise_fma(eaP[i], emP[j],
                                                          (float2v){1.0f, 1.0f});
                    float den = d.x * d.y;
                    float num = __builtin_fmaf(c.x, d.y, c.y * d.x);
                    acc[i][j] = __builtin_fmaf(num, __builtin_amdgcn_rcpf(den),
                                               acc[i][j]);
                }
            }
        }
        __syncthreads();
    }

    // chunk's sum(w2) from sC (sC = -2*w2)
    float w2s = 0.0f;
    for (int k = 0; k < 64; k++) w2s += sC[k].x + sC[k].y;
    w2s *= -0.5f;

    #pragma unroll
    for (int i = 0; i < 2; i++) {
        const int b = b0 + ty * 2 + i;
        #pragma unroll
        for (int j = 0; j < 4; j++)
            atomicAdd(&out[(size_t)b * 2048 + v0 + tx * 4 + j], acc[i][j] + w2s);
    }
}

extern "C" void kernel_launch(void* const* d_in, const int* in_sizes, int n_in,
                              void* d_out, int out_size, void* d_ws, size_t ws_size,
                              hipStream_t stream)
{
    const float* patient = (const float*)d_in[0]; // 256x1024
    const float* atc4    = (const float*)d_in[1]; // 2048x512
    const float* W1      = (const float*)d_in[2]; // 512x1536
    const float* b1      = (const float*)d_in[3]; // 512
    const float* w2      = (const float*)d_in[4]; // 512
    const float* b2      = (const float*)d_in[5]; // 1
    float* out = (float*)d_out;
    float* ws  = (float*)d_ws;

    // ws layout (floats): EA2[256 pairs][256b][2] = 131072, EM2[256][2048][2] = 1048576
    float* EA2 = ws;
    float* EM2 = ws + 131072;

    // Both GEMMs in one dispatch (z selects); exp(2x) epilogue in paired layout;
    // spare z=0 blocks initialize out = b2.
    gemm_exp<<<dim3(32, 8, 2), 256, 0, stream>>>(patient, atc4, W1, b1, b2,
                                                 EA2, EM2, out);
    // score accumulation: one rcp per 2 h-terms, atomicAdd into out
    pair_kernel<<<dim3(32, 8, 4), 256, 0, stream>>>(EA2, EM2, w2, out);
}

// Round 4
// 129.139 us; speedup vs baseline: 1.0305x; 1.0305x over previous
//
#include <hip/hip_runtime.h>
#include <hip/hip_bf16.h>
#include <math.h>

// Problem constants: B=256, V=2048, PD=1024, MD=512, H=512
typedef __attribute__((ext_vector_type(8))) short short8;
typedef __attribute__((ext_vector_type(4))) short short4v;
typedef __attribute__((ext_vector_type(4))) float float4v;
typedef __attribute__((ext_vector_type(2))) float float2v;

__device__ __forceinline__ short f2bf(float f) {
    union { float f; unsigned u; } x; x.f = f;
    unsigned r = (x.u + 0x7FFFu + ((x.u >> 16) & 1u)) >> 16; // RNE
    return (short)r;
}

// Fused dual GEMM + exp epilogue (r2 layout: plain [h][x], contiguous stores).
//  z==0: EA[h][b] = exp(2*(patient@W1p^T + b1))   M=256,  K=1024
//  z==1: EM[h][v] = exp(2*(atc4@W1m^T))           M=2048, K=512
__global__ __launch_bounds__(256) void gemm_exp(
    const float* __restrict__ patient, const float* __restrict__ atc4,
    const float* __restrict__ W1, const float* __restrict__ b1,
    float* __restrict__ EA, float* __restrict__ EM)
{
    const float* A; const float* W; const float* bias; float* T;
    int lda, K, M;
    if (blockIdx.z == 0) {
        if (blockIdx.x >= 4) return;           // 4x8 tiles cover 256x512
        A = patient; lda = 1024; K = 1024; M = 256; bias = b1; T = EA; W = W1;
    } else {
        A = atc4;    lda = 512;  K = 512;  M = 2048; bias = nullptr; T = EM; W = W1 + 1024;
    }
    const int ldw = 1536;

    __shared__ short As[64][72];
    __shared__ short Bs[64][72];
    const int t = threadIdx.x;
    const int m0 = blockIdx.x * 64;
    const int n0 = blockIdx.y * 64;
    const int wave = t >> 6;
    const int lane = t & 63;
    const int wm = (wave & 1) * 32;
    const int wn = (wave >> 1) * 32;
    const int lrow = lane & 15;
    const int quad = lane >> 4;

    float4v acc[2][2];
    #pragma unroll
    for (int i = 0; i < 2; i++)
        #pragma unroll
        for (int j = 0; j < 2; j++)
            acc[i][j] = (float4v){0.f, 0.f, 0.f, 0.f};

    const int sr = t >> 2;        // staging row 0..63
    const int sc = (t & 3) * 16;  // staging col 0,16,32,48

    for (int k0 = 0; k0 < K; k0 += 64) {
        const float* ap = A + (size_t)(m0 + sr) * lda + (k0 + sc);
        const float* wp = W + (size_t)(n0 + sr) * ldw + (k0 + sc);
        #pragma unroll
        for (int ii = 0; ii < 4; ii++) {
            float4v av = *(const float4v*)(ap + ii * 4);
            float4v wv = *(const float4v*)(wp + ii * 4);
            short4v a4 = { f2bf(av.x), f2bf(av.y), f2bf(av.z), f2bf(av.w) };
            short4v w4 = { f2bf(wv.x), f2bf(wv.y), f2bf(wv.z), f2bf(wv.w) };
            *(short4v*)&As[sr][sc + ii * 4] = a4;
            *(short4v*)&Bs[sr][sc + ii * 4] = w4;
        }
        __syncthreads();
        #pragma unroll
        for (int kk = 0; kk < 64; kk += 32) {
            short8 af[2], bfr[2];
            #pragma unroll
            for (int i = 0; i < 2; i++)
                af[i] = *(const short8*)&As[wm + i * 16 + lrow][kk + quad * 8];
            #pragma unroll
            for (int j = 0; j < 2; j++)
                bfr[j] = *(const short8*)&Bs[wn + j * 16 + lrow][kk + quad * 8];
            #pragma unroll
            for (int i = 0; i < 2; i++)
                #pragma unroll
                for (int j = 0; j < 2; j++)
                    acc[i][j] = __builtin_amdgcn_mfma_f32_16x16x32_bf16(
                        af[i], bfr[j], acc[i][j], 0, 0, 0);
        }
        __syncthreads();
    }

    // D layout (verified m89/m91): col(n)=lane&15, row(m)=quad*4+reg
    #pragma unroll
    for (int i = 0; i < 2; i++) {
        #pragma unroll
        for (int j = 0; j < 2; j++) {
            const int n  = n0 + wn + j * 16 + lrow;
            const int mb = m0 + wm + i * 16 + quad * 4;
            const float bn = bias ? bias[n] : 0.0f;
            float4v ev;
            #pragma unroll
            for (int r = 0; r < 4; r++)
                ev[r] = __expf(2.0f * (acc[i][j][r] + bn));
            *(float4v*)&T[(size_t)n * M + mb] = ev;
        }
    }
}

// partial[z][b][v] = sum_{h in chunk z} [ w2[h] + c_h / d_h ],
//   c = -2*w2, d = 1 + Ea[h][b]*Em[h][v]    (w2*tanh(x) = w2 - 2*w2/(1+e^{2x}))
// h-PAIRING via algebra only (layout unchanged, conflict-free strides):
//   c0/d0 + c1/d1 = (c0*d1 + c1*d0) / (d0*d1)   -> one rcp per 2 h-terms.
//   d >= 1 always (e^{2x} > 0), so d0*d1 >= 1: no cancellation/overflow risk.
// Tile: 64 v x 32 b x 128 h. Grid (32, 8, 4) = 1024 blocks.
__global__ __launch_bounds__(256) void pair_kernel(
    const float* __restrict__ EA, const float* __restrict__ EM,
    const float* __restrict__ w2, float* __restrict__ partial)
{
    __shared__ float sEA[64][36];   // [h][b], 32 cols used
    __shared__ float sEM[64][68];   // [h][v], 64 cols used
    __shared__ float2v sC[64];      // (-2w2[h0+2k], -2w2[h0+2k+1])
    const int t  = threadIdx.x;
    const int v0 = blockIdx.x * 64;
    const int b0 = blockIdx.y * 32;
    const int h0 = blockIdx.z * 128;
    const int tx = t & 15;   // v = v0 + tx*4 + j
    const int ty = t >> 4;   // b = b0 + ty*2 + i

    if (t < 64) {
        float2v c = { -2.0f * w2[h0 + 2 * t], -2.0f * w2[h0 + 2 * t + 1] };
        sC[t] = c;
    }

    float acc[2][4];
    #pragma unroll
    for (int i = 0; i < 2; i++)
        #pragma unroll
        for (int j = 0; j < 4; j++)
            acc[i][j] = 0.0f;

    const int rS = t >> 2;          // staging row 0..63
    const int cA = (t & 3) * 8;     // EA cols (32/row)
    const int cM = (t & 3) * 16;    // EM cols (64/row)

    float4v pA0, pA1, pM0, pM1, pM2, pM3;
    // ---- load half 0 ----
    {
        const float* pa = EA + (size_t)(h0 + rS) * 256 + b0 + cA;
        pA0 = *(const float4v*)pa;  pA1 = *(const float4v*)(pa + 4);
        const float* pm = EM + (size_t)(h0 + rS) * 2048 + v0 + cM;
        pM0 = *(const float4v*)pm;      pM1 = *(const float4v*)(pm + 4);
        pM2 = *(const float4v*)(pm + 8); pM3 = *(const float4v*)(pm + 12);
    }
    *(float4v*)&sEA[rS][cA]      = pA0;  *(float4v*)&sEA[rS][cA + 4]  = pA1;
    *(float4v*)&sEM[rS][cM]      = pM0;  *(float4v*)&sEM[rS][cM + 4]  = pM1;
    *(float4v*)&sEM[rS][cM + 8]  = pM2;  *(float4v*)&sEM[rS][cM + 12] = pM3;
    __syncthreads();
    // ---- prefetch half 1 into registers (in flight during compute 0) ----
    {
        const float* pa = EA + (size_t)(h0 + 64 + rS) * 256 + b0 + cA;
        pA0 = *(const float4v*)pa;  pA1 = *(const float4v*)(pa + 4);
        const float* pm = EM + (size_t)(h0 + 64 + rS) * 2048 + v0 + cM;
        pM0 = *(const float4v*)pm;      pM1 = *(const float4v*)(pm + 4);
        pM2 = *(const float4v*)(pm + 8); pM3 = *(const float4v*)(pm + 12);
    }

    #pragma unroll
    for (int half = 0; half < 2; half++) {
        #pragma unroll 2
        for (int hp = 0; hp < 32; hp++) {
            const int ha = 2 * hp, hb = 2 * hp + 1;
            float2v eaP[2];
            eaP[0] = (float2v){ sEA[ha][ty * 2],     sEA[hb][ty * 2]     };
            eaP[1] = (float2v){ sEA[ha][ty * 2 + 1], sEA[hb][ty * 2 + 1] };
            const float4v em0 = *(const float4v*)&sEM[ha][tx * 4];
            const float4v em1 = *(const float4v*)&sEM[hb][tx * 4];
            const float2v c = sC[half * 32 + hp];
            #pragma unroll
            for (int j = 0; j < 4; j++) {
                const float2v em = { em0[j], em1[j] };
                #pragma unroll
                for (int i = 0; i < 2; i++) {
                    float2v d = __builtin_elementwise_fma(eaP[i], em,
                                                          (float2v){1.0f, 1.0f});
                    float den = d.x * d.y;
                    float num = __builtin_fmaf(c.x, d.y, c.y * d.x);
                    acc[i][j] = __builtin_fmaf(num, __builtin_amdgcn_rcpf(den),
                                               acc[i][j]);
                }
            }
        }
        if (half == 0) {
            __syncthreads();   // compute(0) done reading LDS
            *(float4v*)&sEA[rS][cA]      = pA0;  *(float4v*)&sEA[rS][cA + 4]  = pA1;
            *(float4v*)&sEM[rS][cM]      = pM0;  *(float4v*)&sEM[rS][cM + 4]  = pM1;
            *(float4v*)&sEM[rS][cM + 8]  = pM2;  *(float4v*)&sEM[rS][cM + 12] = pM3;
            __syncthreads();
        }
    }

    // chunk's sum(w2) from sC (sC = -2*w2)
    float w2s = 0.0f;
    for (int k = 0; k < 64; k++) w2s += sC[k].x + sC[k].y;
    w2s *= -0.5f;

    const size_t pb = (size_t)blockIdx.z * (256 * 2048);
    #pragma unroll
    for (int i = 0; i < 2; i++) {
        float4v o = { acc[i][0] + w2s, acc[i][1] + w2s,
                      acc[i][2] + w2s, acc[i][3] + w2s };
        *(float4v*)&partial[pb + (size_t)(b0 + ty * 2 + i) * 2048 + v0 + tx * 4] = o;
    }
}

__global__ __launch_bounds__(256) void reduce_kernel(
    const float* __restrict__ partial, const float* __restrict__ b2,
    float* __restrict__ out)
{
    const int i = (blockIdx.x * 256 + threadIdx.x) * 4;
    const float bb = b2[0];
    float4v s0 = *(const float4v*)&partial[i];
    float4v s1 = *(const float4v*)&partial[524288 + i];
    float4v s2 = *(const float4v*)&partial[1048576 + i];
    float4v s3 = *(const float4v*)&partial[1572864 + i];
    float4v o = s0 + s1 + s2 + s3 + bb;
    *(float4v*)&out[i] = o;
}

extern "C" void kernel_launch(void* const* d_in, const int* in_sizes, int n_in,
                              void* d_out, int out_size, void* d_ws, size_t ws_size,
                              hipStream_t stream)
{
    const float* patient = (const float*)d_in[0]; // 256x1024
    const float* atc4    = (const float*)d_in[1]; // 2048x512
    const float* W1      = (const float*)d_in[2]; // 512x1536
    const float* b1      = (const float*)d_in[3]; // 512
    const float* w2      = (const float*)d_in[4]; // 512
    const float* b2      = (const float*)d_in[5]; // 1
    float* out = (float*)d_out;
    float* ws  = (float*)d_ws;

    // ws layout (floats): EA[512][256], EM[512][2048], partial[4][256][2048] => 13.1 MB
    float* EA      = ws;
    float* EM      = ws + 131072;
    float* partial = ws + 1179648;

    // Both GEMMs in one dispatch (z selects); exp(2x) epilogue
    gemm_exp<<<dim3(32, 8, 2), 256, 0, stream>>>(patient, atc4, W1, b1, EA, EM);
    // score partials: one rcp per 2 h-terms, conflict-free LDS strides
    pair_kernel<<<dim3(32, 8, 4), 256, 0, stream>>>(EA, EM, w2, partial);
    // sum 4 h-chunks + b2
    reduce_kernel<<<512, 256, 0, stream>>>(partial, b2, out);
}

// Round 5
// 121.818 us; speedup vs baseline: 1.0925x; 1.0601x over previous
//
#include <hip/hip_runtime.h>
#include <hip/hip_bf16.h>
#include <math.h>

// Problem constants: B=256, V=2048, PD=1024, MD=512, H=512
typedef __attribute__((ext_vector_type(8))) short short8;
typedef __attribute__((ext_vector_type(4))) short short4v;
typedef __attribute__((ext_vector_type(4))) float float4v;
typedef __attribute__((ext_vector_type(2))) float float2v;

__device__ __forceinline__ short f2bf(float f) {
    union { float f; unsigned u; } x; x.f = f;
    unsigned r = (x.u + 0x7FFFu + ((x.u >> 16) & 1u)) >> 16; // RNE
    return (short)r;
}

// Fused dual GEMM + exp epilogue (plain [h][x] layout, contiguous stores).
//  z==0: EA[h][b] = exp(2*(patient@W1p^T + b1))   M=256,  K=1024
//  z==1: EM[h][v] = exp(2*(atc4@W1m^T))           M=2048, K=512
__global__ __launch_bounds__(256) void gemm_exp(
    const float* __restrict__ patient, const float* __restrict__ atc4,
    const float* __restrict__ W1, const float* __restrict__ b1,
    float* __restrict__ EA, float* __restrict__ EM)
{
    const float* A; const float* W; const float* bias; float* T;
    int lda, K, M;
    if (blockIdx.z == 0) {
        if (blockIdx.x >= 4) return;           // 4x8 tiles cover 256x512
        A = patient; lda = 1024; K = 1024; M = 256; bias = b1; T = EA; W = W1;
    } else {
        A = atc4;    lda = 512;  K = 512;  M = 2048; bias = nullptr; T = EM; W = W1 + 1024;
    }
    const int ldw = 1536;

    __shared__ short As[64][72];
    __shared__ short Bs[64][72];
    const int t = threadIdx.x;
    const int m0 = blockIdx.x * 64;
    const int n0 = blockIdx.y * 64;
    const int wave = t >> 6;
    const int lane = t & 63;
    const int wm = (wave & 1) * 32;
    const int wn = (wave >> 1) * 32;
    const int lrow = lane & 15;
    const int quad = lane >> 4;

    float4v acc[2][2];
    #pragma unroll
    for (int i = 0; i < 2; i++)
        #pragma unroll
        for (int j = 0; j < 2; j++)
            acc[i][j] = (float4v){0.f, 0.f, 0.f, 0.f};

    const int sr = t >> 2;        // staging row 0..63
    const int sc = (t & 3) * 16;  // staging col 0,16,32,48

    for (int k0 = 0; k0 < K; k0 += 64) {
        const float* ap = A + (size_t)(m0 + sr) * lda + (k0 + sc);
        const float* wp = W + (size_t)(n0 + sr) * ldw + (k0 + sc);
        #pragma unroll
        for (int ii = 0; ii < 4; ii++) {
            float4v av = *(const float4v*)(ap + ii * 4);
            float4v wv = *(const float4v*)(wp + ii * 4);
            short4v a4 = { f2bf(av.x), f2bf(av.y), f2bf(av.z), f2bf(av.w) };
            short4v w4 = { f2bf(wv.x), f2bf(wv.y), f2bf(wv.z), f2bf(wv.w) };
            *(short4v*)&As[sr][sc + ii * 4] = a4;
            *(short4v*)&Bs[sr][sc + ii * 4] = w4;
        }
        __syncthreads();
        #pragma unroll
        for (int kk = 0; kk < 64; kk += 32) {
            short8 af[2], bfr[2];
            #pragma unroll
            for (int i = 0; i < 2; i++)
                af[i] = *(const short8*)&As[wm + i * 16 + lrow][kk + quad * 8];
            #pragma unroll
            for (int j = 0; j < 2; j++)
                bfr[j] = *(const short8*)&Bs[wn + j * 16 + lrow][kk + quad * 8];
            #pragma unroll
            for (int i = 0; i < 2; i++)
                #pragma unroll
                for (int j = 0; j < 2; j++)
                    acc[i][j] = __builtin_amdgcn_mfma_f32_16x16x32_bf16(
                        af[i], bfr[j], acc[i][j], 0, 0, 0);
        }
        __syncthreads();
    }

    // D layout (verified m89/m91): col(n)=lane&15, row(m)=quad*4+reg
    #pragma unroll
    for (int i = 0; i < 2; i++) {
        #pragma unroll
        for (int j = 0; j < 2; j++) {
            const int n  = n0 + wn + j * 16 + lrow;
            const int mb = m0 + wm + i * 16 + quad * 4;
            const float bn = bias ? bias[n] : 0.0f;
            float4v ev;
            #pragma unroll
            for (int r = 0; r < 4; r++)
                ev[r] = __expf(2.0f * (acc[i][j][r] + bn));
            *(float4v*)&T[(size_t)n * M + mb] = ev;
        }
    }
}

// partial[z][b][v] = sum_{h in 64-chunk z} [ w2[h] + c_h / d_h ],
//   c = -2*w2, d = 1 + Ea[h][b]*Em[h][v]    (w2*tanh(x) = w2 - 2*w2/(1+e^{2x}))
// h-pairing (one rcp / 2 h): c0/d0 + c1/d1 = (c0*d1 + c1*d0)/(d0*d1); d >= 1 always.
// Vectorized across the 4 v per thread: d0,d1,den,num,acc are float4 pk-ops; the
// scalar operands (ea, c) splat for free -> no packing movs.
// Tile: 64 v x 32 b x 64 h. Grid (32, 8, 8) = 2048 blocks (8/CU -> full occupancy).
__global__ __launch_bounds__(256, 8) void pair_kernel(
    const float* __restrict__ EA, const float* __restrict__ EM,
    const float* __restrict__ w2, float* __restrict__ partial)
{
    __shared__ float sEA[32][36];   // [h][b], 32 cols used
    __shared__ float sEM[32][68];   // [h][v], 64 cols used
    __shared__ float2v sC[32];      // (-2w2[h0+2k], -2w2[h0+2k+1])
    const int t  = threadIdx.x;
    const int v0 = blockIdx.x * 64;
    const int b0 = blockIdx.y * 32;
    const int h0 = blockIdx.z * 64;
    const int tx = t & 15;   // v = v0 + tx*4 + j
    const int ty = t >> 4;   // b = b0 + ty*2 + i

    if (t < 32) {
        float2v c = { -2.0f * w2[h0 + 2 * t], -2.0f * w2[h0 + 2 * t + 1] };
        sC[t] = c;
    }

    float4v acc[2];
    acc[0] = (float4v){0.f, 0.f, 0.f, 0.f};
    acc[1] = (float4v){0.f, 0.f, 0.f, 0.f};
    const float4v one4 = {1.f, 1.f, 1.f, 1.f};

    const int rS = t >> 3;          // staging row 0..31
    const int cA = (t & 7) * 4;     // EA cols (32/row, 1 float4)
    const int cM = (t & 7) * 8;     // EM cols (64/row, 2 float4)

    float4v pA, pM0, pM1;
    // ---- load half 0 (h0 .. h0+31) ----
    {
        pA  = *(const float4v*)(EA + (size_t)(h0 + rS) * 256 + b0 + cA);
        const float* pm = EM + (size_t)(h0 + rS) * 2048 + v0 + cM;
        pM0 = *(const float4v*)pm;  pM1 = *(const float4v*)(pm + 4);
    }
    *(float4v*)&sEA[rS][cA] = pA;
    *(float4v*)&sEM[rS][cM] = pM0;  *(float4v*)&sEM[rS][cM + 4] = pM1;
    __syncthreads();
    // ---- prefetch half 1 into registers (in flight during compute 0) ----
    {
        pA  = *(const float4v*)(EA + (size_t)(h0 + 32 + rS) * 256 + b0 + cA);
        const float* pm = EM + (size_t)(h0 + 32 + rS) * 2048 + v0 + cM;
        pM0 = *(const float4v*)pm;  pM1 = *(const float4v*)(pm + 4);
    }

    #pragma unroll
    for (int half = 0; half < 2; half++) {
        #pragma unroll 2
        for (int hp = 0; hp < 16; hp++) {
            const int ha = 2 * hp, hb = 2 * hp + 1;
            const float4v em0 = *(const float4v*)&sEM[ha][tx * 4];
            const float4v em1 = *(const float4v*)&sEM[hb][tx * 4];
            const float2v c = sC[half * 16 + hp];
            const float4v c0 = { c.x, c.x, c.x, c.x };
            const float4v c1 = { c.y, c.y, c.y, c.y };
            #pragma unroll
            for (int i = 0; i < 2; i++) {
                const float ea0 = sEA[ha][ty * 2 + i];
                const float ea1 = sEA[hb][ty * 2 + i];
                const float4v ea0v = { ea0, ea0, ea0, ea0 };
                const float4v ea1v = { ea1, ea1, ea1, ea1 };
                float4v d0  = __builtin_elementwise_fma(em0, ea0v, one4);
                float4v d1  = __builtin_elementwise_fma(em1, ea1v, one4);
                float4v den = d0 * d1;
                float4v num = __builtin_elementwise_fma(d1, c0, d0 * c1);
                float4v r = { __builtin_amdgcn_rcpf(den.x),
                              __builtin_amdgcn_rcpf(den.y),
                              __builtin_amdgcn_rcpf(den.z),
                              __builtin_amdgcn_rcpf(den.w) };
                acc[i] = __builtin_elementwise_fma(num, r, acc[i]);
            }
        }
        if (half == 0) {
            __syncthreads();   // compute(0) done reading LDS
            *(float4v*)&sEA[rS][cA] = pA;
            *(float4v*)&sEM[rS][cM] = pM0;  *(float4v*)&sEM[rS][cM + 4] = pM1;
            __syncthreads();
        }
    }

    // chunk's sum(w2) from sC (sC = -2*w2)
    float2v w2p = sC[0];
    for (int k = 1; k < 32; k++) w2p += sC[k];
    const float w2s = -0.5f * (w2p.x + w2p.y);

    const size_t pb = (size_t)blockIdx.z * (256 * 2048);
    #pragma unroll
    for (int i = 0; i < 2; i++) {
        float4v o = acc[i] + w2s;
        *(float4v*)&partial[pb + (size_t)(b0 + ty * 2 + i) * 2048 + v0 + tx * 4] = o;
    }
}

__global__ __launch_bounds__(256) void reduce_kernel(
    const float* __restrict__ partial, const float* __restrict__ b2,
    float* __restrict__ out)
{
    const int i = (blockIdx.x * 256 + threadIdx.x) * 4;
    const float bb = b2[0];
    float4v s = *(const float4v*)&partial[i];
    #pragma unroll
    for (int z = 1; z < 8; z++)
        s += *(const float4v*)&partial[(size_t)z * 524288 + i];
    float4v o = s + bb;
    *(float4v*)&out[i] = o;
}

extern "C" void kernel_launch(void* const* d_in, const int* in_sizes, int n_in,
                              void* d_out, int out_size, void* d_ws, size_t ws_size,
                              hipStream_t stream)
{
    const float* patient = (const float*)d_in[0]; // 256x1024
    const float* atc4    = (const float*)d_in[1]; // 2048x512
    const float* W1      = (const float*)d_in[2]; // 512x1536
    const float* b1      = (const float*)d_in[3]; // 512
    const float* w2      = (const float*)d_in[4]; // 512
    const float* b2      = (const float*)d_in[5]; // 1
    float* out = (float*)d_out;
    float* ws  = (float*)d_ws;

    // ws layout (floats): EA[512][256], EM[512][2048], partial[8][256][2048] => 21.5 MB
    float* EA      = ws;
    float* EM      = ws + 131072;
    float* partial = ws + 1179648;

    // Both GEMMs in one dispatch (z selects); exp(2x) epilogue
    gemm_exp<<<dim3(32, 8, 2), 256, 0, stream>>>(patient, atc4, W1, b1, EA, EM);
    // score partials: float4-across-v pk math, one rcp per 2 h-terms
    pair_kernel<<<dim3(32, 8, 8), 256, 0, stream>>>(EA, EM, w2, partial);
    // sum 8 h-chunks + b2
    reduce_kernel<<<512, 256, 0, stream>>>(partial, b2, out);
}